// Round 10
// baseline (133.906 us; speedup 1.0000x reference)
//
#include <hip/hip_runtime.h>
#include <stdint.h>

#define EPSF 1e-8f

using i32x4 = __attribute__((ext_vector_type(4))) int;

__device__ __forceinline__ float wave_sum(float v) {
#pragma unroll
  for (int off = 32; off > 0; off >>= 1) v += __shfl_down(v, off, 64);
  return v;
}
__device__ __forceinline__ float wave_max(float v) {
#pragma unroll
  for (int off = 32; off > 0; off >>= 1) v = fmaxf(v, __shfl_down(v, off, 64));
  return v;
}

// ---------------- fused prep: wquant (blocks 0..Dout-1) + xnorm (rest) ----
__global__ __launch_bounds__(256) void prep_kernel(
    const float* __restrict__ x, const float* __restrict__ g,
    const float* __restrict__ w, const float* __restrict__ row_scale,
    signed char* __restrict__ xq, float* __restrict__ sx,
    signed char* __restrict__ wq, float* __restrict__ scale,
    int K, int Dout) {
  __shared__ float smA[4], smQ[4], smM[4];
  const int t = threadIdx.x;
  const int wid = t >> 6;
  if ((int)blockIdx.x < Dout) {
    const int row = blockIdx.x;
    const float* wr = w + (size_t)row * K;
    float4 v0 = reinterpret_cast<const float4*>(wr)[2 * t];
    float4 v1 = reinterpret_cast<const float4*>(wr)[2 * t + 1];
    float f[8] = {v0.x, v0.y, v0.z, v0.w, v1.x, v1.y, v1.z, v1.w};
    float sa = 0.f, sq = 0.f;
#pragma unroll
    for (int i = 0; i < 8; ++i) { sa += fabsf(f[i]); sq += f[i] * f[i]; }
    sa = wave_sum(sa);
    sq = wave_sum(sq);
    if ((t & 63) == 0) { smA[wid] = sa; smQ[wid] = sq; }
    __syncthreads();
    const float sumabs = smA[0] + smA[1] + smA[2] + smA[3];
    const float sumsq  = smQ[0] + smQ[1] + smQ[2] + smQ[3];
    const float absmean = sumabs / (float)K;
    const float thr = 0.5f * absmean;
    union { signed char c[8]; uint2 u; } pk;
#pragma unroll
    for (int i = 0; i < 8; ++i)
      pk.c[i] = (fabsf(f[i]) > thr)
                    ? (f[i] > 0.f ? (signed char)1 : (signed char)-1)
                    : (signed char)0;
    reinterpret_cast<uint2*>(wq + (size_t)row * K)[t] = pk.u;
    if (t == 0)
      scale[row] = absmean * rsqrtf(sumsq / (float)K + EPSF) * row_scale[row];
  } else {
    const int row = blockIdx.x - Dout;
    const float* xr = x + (size_t)row * K;
    float4 v0 = reinterpret_cast<const float4*>(xr)[2 * t];
    float4 v1 = reinterpret_cast<const float4*>(xr)[2 * t + 1];
    float f[8] = {v0.x, v0.y, v0.z, v0.w, v1.x, v1.y, v1.z, v1.w};
    float sq = 0.f;
#pragma unroll
    for (int i = 0; i < 8; ++i) sq += f[i] * f[i];
    sq = wave_sum(sq);
    if ((t & 63) == 0) smQ[wid] = sq;
    __syncthreads();
    const float sumsq = smQ[0] + smQ[1] + smQ[2] + smQ[3];
    const float rs = rsqrtf(sumsq / (float)K + EPSF);
    float4 g0 = reinterpret_cast<const float4*>(g)[2 * t];
    float4 g1 = reinterpret_cast<const float4*>(g)[2 * t + 1];
    float gg[8] = {g0.x, g0.y, g0.z, g0.w, g1.x, g1.y, g1.z, g1.w};
    float vv[8]; float am = 0.f;
#pragma unroll
    for (int i = 0; i < 8; ++i) {
      vv[i] = f[i] * rs * gg[i];
      am = fmaxf(am, fabsf(vv[i]));
    }
    am = wave_max(am);
    if ((t & 63) == 0) smM[wid] = am;
    __syncthreads();
    const float amax = fmaxf(fmaxf(smM[0], smM[1]), fmaxf(smM[2], smM[3]));
    const float inv = amax > 0.f ? 127.f / amax : 0.f;
    union { signed char c[8]; uint2 u; } pk;
#pragma unroll
    for (int i = 0; i < 8; ++i)
      pk.c[i] = (signed char)__float2int_rn(vv[i] * inv);
    reinterpret_cast<uint2*>(xq + (size_t)row * K)[t] = pk.u;
    if (t == 0) sx[row] = amax > 0.f ? amax / 127.f : 0.f;
  }
}

// ---------------- i8 NT GEMM, persistent 2-tile blocks ----------------
// ROUND-10: R6 structure (best measured) + each block does TWO output tiles
// (same bm, adjacent bn) -> grid 256 = 1 block/CU, single round.
//  * tile-1's store-peel weaves in tile-2's prologue staging: stores overlap
//    the next tile's HBM reads (the serialization R9 showed: all schedules
//    behave ~sum-of-floors; the guaranteed-serial piece was epilogue stores
//    vs next-block prologue, since 128 KiB LDS pins 1 block/CU).
//  * A panel staged once for both tiles (same bm) -> FETCH drops ~25%.
// Woven-peel vmcnt ledger (load units; stage = 2 loads):
//  enter 8 {A0h1,B0h1,A1h0,B1h0}; P1 +A11=10 VM(6)->6 (drains A0h1,B0h1;
//  read P2/P3); P2 +B11=8; P4 VM(4)->4 (drains A1h0,B1h0; read P5);
//  P5 +A00',B00'=8 VM(4)->4 (drains A11,B11; read P6/P7); P6 +A01'=6;
//  P7 +B01'=8; P8 +A10'=10; TR +B10'=12 VM(8)->8 (drains A00',B00'; read
//  tile-2 P1) = exactly the main-loop entering invariant.
// Write-hazard (>=1 barrier after last readers): P5 wr buf0h0 (last rd P1,
// all waves past P4-BAR); P6 wr buf0A-h1 (rd P3, past P5-BAR); P7 wr
// buf0B-h1 (rd P2); P8 wr buf1h0-A (rd P5, past P7-BAR); TR wr buf1h0-B
// (rd P5, past P8-BAR); tile-2 P1/P2 wr buf1h1 (rd peel P6/P7, past TR-BAR).

#define BAR() do { __builtin_amdgcn_sched_barrier(0); \
                   asm volatile("" ::: "memory"); \
                   __builtin_amdgcn_s_barrier(); \
                   asm volatile("" ::: "memory"); \
                   __builtin_amdgcn_sched_barrier(0); } while (0)
#define VM(n) asm volatile("s_waitcnt vmcnt(" #n ")" ::: "memory")

__global__ __launch_bounds__(512, 2) void gemm_kernel(
    const signed char* __restrict__ A,   // [M][K] i8 (xq)
    const signed char* __restrict__ B,   // [N][K] i8 ternary (wq)
    const float* __restrict__ scale, const float* __restrict__ bias,
    const float* __restrict__ sx,
    float* __restrict__ C, int M, int N, int K) {
  __shared__ signed char lds[2][2][2][16384];

  const int tid  = threadIdx.x;
  const int lane = tid & 63;
  const int wid  = tid >> 6;
  const int wm   = wid >> 2;   // 0..1
  const int wn   = wid & 3;    // 0..3
  const int fr   = lane & 15;
  const int kq   = lane >> 4;

  // chunked XCD swizzle; grid = (M/256)*(N/512), 256 % 8 == 0
  const int nwg = gridDim.x;
  const int cpx = nwg >> 3;
  const int swz = (blockIdx.x & 7) * cpx + (blockIdx.x >> 3);
  const int NBP = N >> 9;                 // 512-wide column pairs
  const int bp = swz % NBP;
  const int bm = swz / NBP;
  const int mBase = bm * 256;
  const int nBase1 = bp * 512;            // tile 1 columns
  const int nBase2 = nBase1 + 256;        // tile 2 columns

  const size_t Kb = (size_t)K;

  // staging: thread t -> lds row sr=t>>3, granule slot t&7; XOR-inverse
  // source granule (valid for +64-row second load: 64&7==0).
  const int sr = tid >> 3;
  const int gsrc = (tid & 7) ^ (sr & 7);
  const char* Abyte = (const char*)A + (size_t)(mBase + sr) * Kb + gsrc * 16;
  const char* Bbyte = (const char*)B +
      (size_t)(nBase1 + ((sr >> 5) * 64) + (sr & 31)) * Kb + gsrc * 16;
  const size_t bOff2 = (size_t)256 * Kb;  // tile-2 B offset

#define STAGE_A(bufi, h, t) do { \
    __builtin_amdgcn_global_load_lds( \
      (const __attribute__((address_space(1))) void*)(Abyte + (size_t)((h) * 64) * Kb + (size_t)(t) * 128), \
      (__attribute__((address_space(3))) void*)(&lds[bufi][0][h][tid * 16]), 16, 0, 0); \
    __builtin_amdgcn_global_load_lds( \
      (const __attribute__((address_space(1))) void*)(Abyte + (size_t)(128 + (h) * 64) * Kb + (size_t)(t) * 128), \
      (__attribute__((address_space(3))) void*)(&lds[bufi][0][h][8192 + tid * 16]), 16, 0, 0); \
  } while (0)

#define STAGE_B(bufi, h, t, bo) do { \
    __builtin_amdgcn_global_load_lds( \
      (const __attribute__((address_space(1))) void*)(Bbyte + (bo) + (size_t)((h) * 32) * Kb + (size_t)(t) * 128), \
      (__attribute__((address_space(3))) void*)(&lds[bufi][1][h][tid * 16]), 16, 0, 0); \
    __builtin_amdgcn_global_load_lds( \
      (const __attribute__((address_space(1))) void*)(Bbyte + (bo) + (size_t)(128 + (h) * 32) * Kb + (size_t)(t) * 128), \
      (__attribute__((address_space(3))) void*)(&lds[bufi][1][h][8192 + tid * 16]), 16, 0, 0); \
  } while (0)

  // reader constants (XOR perm; fragment rows ≡ fr mod 8)
  const int slot0 = ((kq ^ (fr & 7)) << 4);
  const int aRowB = (wm * 64 + fr) * 128;
  const int bRowB = (wn * 32 + fr) * 128;

  i32x4 aF[4][2], bF[4][2];
  i32x4 acc[8][4];
#pragma unroll
  for (int m = 0; m < 8; ++m)
#pragma unroll
    for (int n = 0; n < 4; ++n) acc[m][n] = (i32x4){0, 0, 0, 0};

#define LDA(bufi, mg) do { \
    _Pragma("unroll") for (int mm = 0; mm < 4; ++mm) \
    _Pragma("unroll") for (int s = 0; s < 2; ++s) \
      aF[mm][s] = *(const i32x4*)&lds[bufi][0][mg][ \
          aRowB + mm * 2048 + (slot0 ^ (s << 6))]; \
  } while (0)

#define LDB(bufi, np) do { \
    _Pragma("unroll") for (int nn = 0; nn < 2; ++nn) \
    _Pragma("unroll") for (int s = 0; s < 2; ++s) \
      bF[(np) * 2 + nn][s] = *(const i32x4*)&lds[bufi][1][np][ \
          bRowB + nn * 2048 + (slot0 ^ (s << 6))]; \
  } while (0)

#define MFMA_Q(mg, np) do { \
    __builtin_amdgcn_s_setprio(1); \
    _Pragma("unroll") for (int mm = 0; mm < 4; ++mm) \
    _Pragma("unroll") for (int nn = 0; nn < 2; ++nn) { \
      i32x4 c = acc[(mg) * 4 + mm][(np) * 2 + nn]; \
      c = __builtin_amdgcn_mfma_i32_16x16x64_i8(aF[mm][0], bF[(np) * 2 + nn][0], c, 0, 0, 0); \
      c = __builtin_amdgcn_mfma_i32_16x16x64_i8(aF[mm][1], bF[(np) * 2 + nn][1], c, 0, 0, 0); \
      acc[(mg) * 4 + mm][(np) * 2 + nn] = c; \
    } \
    __builtin_amdgcn_s_setprio(0); } while (0)

  const int crowBase = mBase + wm * 128 + kq * 4;

#define STORE_Q(mg, np, cb) do { \
    float sxq_[4][4]; \
    _Pragma("unroll") for (int mm = 0; mm < 4; ++mm) \
    _Pragma("unroll") for (int r = 0; r < 4; ++r) \
      sxq_[mm][r] = sx[crowBase + ((mg) * 4 + mm) * 16 + r]; \
    _Pragma("unroll") for (int nn = 0; nn < 2; ++nn) { \
      const int gc = (cb) + ((np) * 2 + nn) * 16; \
      const float sc = scale[gc]; \
      const float bi = bias[gc]; \
      _Pragma("unroll") for (int mm = 0; mm < 4; ++mm) { \
        const int r0 = crowBase + ((mg) * 4 + mm) * 16; \
        _Pragma("unroll") for (int r = 0; r < 4; ++r) \
          C[(size_t)(r0 + r) * (size_t)N + (size_t)gc] = \
              (float)acc[(mg) * 4 + mm][(np) * 2 + nn][r] * (sxq_[mm][r] * sc) + bi; \
      } } } while (0)

  const int ccol1 = nBase1 + wn * 64 + fr;
  const int ccol2 = nBase2 + wn * 64 + fr;
  const int NT = K >> 7;  // 16

  // ================= tile 1 =================
  STAGE_A(0, 0, 0); STAGE_B(0, 0, 0, 0);
  STAGE_A(0, 1, 0); STAGE_B(0, 1, 0, 0);
  STAGE_A(1, 0, 1); STAGE_B(1, 0, 1, 0);
  VM(8);
  BAR();

  for (int i = 0; i < (NT >> 1) - 1; ++i) {
    const int t1  = 2 * i + 1;
    const int tn0 = 2 * i + 2;
    const int tn1 = 2 * i + 3;
    LDA(0, 0); LDB(0, 0); STAGE_A(1, 1, t1); VM(6);
    BAR(); MFMA_Q(0, 0);
    LDB(0, 1); STAGE_B(1, 1, t1, 0);
    BAR(); MFMA_Q(0, 1);
    LDA(0, 1); STAGE_A(0, 0, tn0);
    BAR(); MFMA_Q(1, 0);
    STAGE_B(0, 0, tn0, 0); VM(8);
    BAR(); MFMA_Q(1, 1);
    LDA(1, 0); LDB(1, 0); STAGE_A(0, 1, tn0); VM(6);
    BAR(); MFMA_Q(0, 0);
    LDB(1, 1); STAGE_B(0, 1, tn0, 0);
    BAR(); MFMA_Q(0, 1);
    LDA(1, 1); STAGE_A(1, 0, tn1);
    BAR(); MFMA_Q(1, 0);
    STAGE_B(1, 0, tn1, 0); VM(8);
    BAR(); MFMA_Q(1, 1);
  }

  // ---- tile-1 peel, woven with tile-2 prologue staging ----
  {
    const int tl = NT - 1;
    // P1
    LDA(0, 0); LDB(0, 0); STAGE_A(1, 1, tl); VM(6);
    BAR(); MFMA_Q(0, 0);
    // P2
    LDB(0, 1); STAGE_B(1, 1, tl, 0);
    BAR(); MFMA_Q(0, 1);
    // P3
    LDA(0, 1);
    BAR(); MFMA_Q(1, 0);
    // P4: drain buf1 h0 pair (read P5)
    VM(4);
    BAR(); MFMA_Q(1, 1);
    // P5: + tile-2 t0 h0 stages; drain A11,B11 (read P6/P7); store (0,0)
    LDA(1, 0); LDB(1, 0);
    STAGE_A(0, 0, 0); STAGE_B(0, 0, 0, bOff2);
    VM(4);
    BAR(); MFMA_Q(0, 0); STORE_Q(0, 0, ccol1);
    // P6
    LDB(1, 1); STAGE_A(0, 1, 0);
    BAR(); MFMA_Q(0, 1); STORE_Q(0, 1, ccol1);
    // P7
    LDA(1, 1); STAGE_B(0, 1, 0, bOff2);
    BAR(); MFMA_Q(1, 0); STORE_Q(1, 0, ccol1);
    // P8
    STAGE_A(1, 0, 1);
    BAR(); MFMA_Q(1, 1); STORE_Q(1, 1, ccol1);
    // TR: finish tile-2 prologue; drain t0 h0 (read tile-2 P1); reset acc
    STAGE_B(1, 0, 1, bOff2);
    VM(8);
#pragma unroll
    for (int m = 0; m < 8; ++m)
#pragma unroll
      for (int n = 0; n < 4; ++n) acc[m][n] = (i32x4){0, 0, 0, 0};
    BAR();
  }

  // ================= tile 2 =================
  for (int i = 0; i < (NT >> 1) - 1; ++i) {
    const int t1  = 2 * i + 1;
    const int tn0 = 2 * i + 2;
    const int tn1 = 2 * i + 3;
    LDA(0, 0); LDB(0, 0); STAGE_A(1, 1, t1); VM(6);
    BAR(); MFMA_Q(0, 0);
    LDB(0, 1); STAGE_B(1, 1, t1, bOff2);
    BAR(); MFMA_Q(0, 1);
    LDA(0, 1); STAGE_A(0, 0, tn0);
    BAR(); MFMA_Q(1, 0);
    STAGE_B(0, 0, tn0, bOff2); VM(8);
    BAR(); MFMA_Q(1, 1);
    LDA(1, 0); LDB(1, 0); STAGE_A(0, 1, tn0); VM(6);
    BAR(); MFMA_Q(0, 0);
    LDB(1, 1); STAGE_B(0, 1, tn0, bOff2);
    BAR(); MFMA_Q(0, 1);
    LDA(1, 1); STAGE_A(1, 0, tn1);
    BAR(); MFMA_Q(1, 0);
    STAGE_B(1, 0, tn1, bOff2); VM(8);
    BAR(); MFMA_Q(1, 1);
  }

  // ---- tile-2 peel (standard R6 peel, tile-2 columns) ----
  {
    const int tl = NT - 1;
    LDA(0, 0); LDB(0, 0); STAGE_A(1, 1, tl); VM(6);
    BAR(); MFMA_Q(0, 0);
    LDB(0, 1); STAGE_B(1, 1, tl, bOff2);
    BAR(); MFMA_Q(0, 1);
    LDA(0, 1);
    BAR(); MFMA_Q(1, 0);
    VM(4);
    BAR(); MFMA_Q(1, 1);
    LDA(1, 0); LDB(1, 0); VM(0);
    BAR(); MFMA_Q(0, 0); STORE_Q(0, 0, ccol2);
    LDB(1, 1);
    BAR(); MFMA_Q(0, 1); STORE_Q(0, 1, ccol2);
    LDA(1, 1);
    BAR(); MFMA_Q(1, 0); STORE_Q(1, 0, ccol2);
    BAR(); MFMA_Q(1, 1); STORE_Q(1, 1, ccol2);
  }
#undef STAGE_A
#undef STAGE_B
#undef LDA
#undef LDB
#undef MFMA_Q
#undef STORE_Q
}

extern "C" void kernel_launch(void* const* d_in, const int* in_sizes, int n_in,
                              void* d_out, int out_size, void* d_ws, size_t ws_size,
                              hipStream_t stream) {
  const float* x         = (const float*)d_in[0];  // [B,S,Din]
  const float* weight    = (const float*)d_in[1];  // [Dout,Din]
  const float* row_scale = (const float*)d_in[2];  // [Dout,1]
  const float* bias      = (const float*)d_in[3];  // [Dout]
  const float* g         = (const float*)d_in[4];  // [Din]
  float* out = (float*)d_out;

  const int Din  = in_sizes[4];         // 2048
  const int Dout = in_sizes[3];         // 2048
  const int Mrows = in_sizes[0] / Din;  // 16384

  // ws: wq i8 [Dout*Din] | xq i8 [M*Din] | scale f32 [Dout] | sx f32 [M]
  char* ws = (char*)d_ws;
  signed char* wq = (signed char*)ws;
  signed char* xq = (signed char*)(ws + (size_t)Dout * Din);
  float* scale = (float*)(ws + (size_t)Dout * Din + (size_t)Mrows * Din);
  float* sx = scale + Dout;

  prep_kernel<<<Dout + Mrows, 256, 0, stream>>>(x, g, weight, row_scale,
                                                xq, sx, wq, scale, Din, Dout);
  const int grid = (Mrows / 256) * (Dout / 512);  // 64 * 4 = 256
  gemm_kernel<<<grid, 512, 0, stream>>>(xq, wq, scale, bias, sx, out,
                                        Mrows, Dout, Din);
}

// Round 11
// 122.392 us; speedup vs baseline: 1.0941x; 1.0941x over previous
//
#include <hip/hip_runtime.h>
#include <stdint.h>

#define EPSF 1e-8f

using i32x4 = __attribute__((ext_vector_type(4))) int;

__device__ __forceinline__ float wave_sum(float v) {
#pragma unroll
  for (int off = 32; off > 0; off >>= 1) v += __shfl_down(v, off, 64);
  return v;
}
__device__ __forceinline__ float wave_max(float v) {
#pragma unroll
  for (int off = 32; off > 0; off >>= 1) v = fmaxf(v, __shfl_down(v, off, 64));
  return v;
}

// ---------------- fused prep: wquant (blocks 0..Dout-1) + xnorm (rest) ----
__global__ __launch_bounds__(256) void prep_kernel(
    const float* __restrict__ x, const float* __restrict__ g,
    const float* __restrict__ w, const float* __restrict__ row_scale,
    signed char* __restrict__ xq, float* __restrict__ sx,
    signed char* __restrict__ wq, float* __restrict__ scale,
    int K, int Dout) {
  __shared__ float smA[4], smQ[4], smM[4];
  const int t = threadIdx.x;
  const int wid = t >> 6;
  if ((int)blockIdx.x < Dout) {
    const int row = blockIdx.x;
    const float* wr = w + (size_t)row * K;
    float4 v0 = reinterpret_cast<const float4*>(wr)[2 * t];
    float4 v1 = reinterpret_cast<const float4*>(wr)[2 * t + 1];
    float f[8] = {v0.x, v0.y, v0.z, v0.w, v1.x, v1.y, v1.z, v1.w};
    float sa = 0.f, sq = 0.f;
#pragma unroll
    for (int i = 0; i < 8; ++i) { sa += fabsf(f[i]); sq += f[i] * f[i]; }
    sa = wave_sum(sa);
    sq = wave_sum(sq);
    if ((t & 63) == 0) { smA[wid] = sa; smQ[wid] = sq; }
    __syncthreads();
    const float sumabs = smA[0] + smA[1] + smA[2] + smA[3];
    const float sumsq  = smQ[0] + smQ[1] + smQ[2] + smQ[3];
    const float absmean = sumabs / (float)K;
    const float thr = 0.5f * absmean;
    union { signed char c[8]; uint2 u; } pk;
#pragma unroll
    for (int i = 0; i < 8; ++i)
      pk.c[i] = (fabsf(f[i]) > thr)
                    ? (f[i] > 0.f ? (signed char)1 : (signed char)-1)
                    : (signed char)0;
    reinterpret_cast<uint2*>(wq + (size_t)row * K)[t] = pk.u;
    if (t == 0)
      scale[row] = absmean * rsqrtf(sumsq / (float)K + EPSF) * row_scale[row];
  } else {
    const int row = blockIdx.x - Dout;
    const float* xr = x + (size_t)row * K;
    float4 v0 = reinterpret_cast<const float4*>(xr)[2 * t];
    float4 v1 = reinterpret_cast<const float4*>(xr)[2 * t + 1];
    float f[8] = {v0.x, v0.y, v0.z, v0.w, v1.x, v1.y, v1.z, v1.w};
    float sq = 0.f;
#pragma unroll
    for (int i = 0; i < 8; ++i) sq += f[i] * f[i];
    sq = wave_sum(sq);
    if ((t & 63) == 0) smQ[wid] = sq;
    __syncthreads();
    const float sumsq = smQ[0] + smQ[1] + smQ[2] + smQ[3];
    const float rs = rsqrtf(sumsq / (float)K + EPSF);
    float4 g0 = reinterpret_cast<const float4*>(g)[2 * t];
    float4 g1 = reinterpret_cast<const float4*>(g)[2 * t + 1];
    float gg[8] = {g0.x, g0.y, g0.z, g0.w, g1.x, g1.y, g1.z, g1.w};
    float vv[8]; float am = 0.f;
#pragma unroll
    for (int i = 0; i < 8; ++i) {
      vv[i] = f[i] * rs * gg[i];
      am = fmaxf(am, fabsf(vv[i]));
    }
    am = wave_max(am);
    if ((t & 63) == 0) smM[wid] = am;
    __syncthreads();
    const float amax = fmaxf(fmaxf(smM[0], smM[1]), fmaxf(smM[2], smM[3]));
    const float inv = amax > 0.f ? 127.f / amax : 0.f;
    union { signed char c[8]; uint2 u; } pk;
#pragma unroll
    for (int i = 0; i < 8; ++i)
      pk.c[i] = (signed char)__float2int_rn(vv[i] * inv);
    reinterpret_cast<uint2*>(xq + (size_t)row * K)[t] = pk.u;
    if (t == 0) sx[row] = amax > 0.f ? amax / 127.f : 0.f;
  }
}

// ---------------- i8 NT GEMM, 256x128 tile, 4 waves/SIMD ----------------
// ROUND-11: occupancy-driven overlap. R6/R8/R9 all measured = LDS-cycles +
// MFMA-cycles SUMMED (per-CU ~184-190k cyc = ~100k LDS + 84k MFMA): with
// only 2 barrier-aligned waves/SIMD, every wave reads-then-MFMAs in
// lockstep, so the CU LDS pipe and MFMA pipe alternate instead of overlap.
// Fix: per-wave output 64x64 -> acc 64 + aF 16 + bF 16 + addr ~= 115 VGPR
// <= 128 -> 4 waves/SIMD. 8-wave blocks (2Mx... wave grid 4Mx2N), tile
// 256x128, BK=64, triple-buffered LDS 3x24KB = 72 KB -> 2 blocks/CU =
// 16 waves/CU, blocks mutually unsynchronized (independent barriers).
// Schedule (R9's validated single-region): per K-tile t:
//   VM(3); BAR; stage(t+2) into buf (t+2)%3; 8 ds_read_b128; 16 MFMA.
// vmcnt ledger (stage = 3 gload_lds: 2 A + 1 B): prologue stages t0,t1 = 6;
// tile t: VM(3) drains stage(t) (reads follow), stage(t+2) -> 6.
// Tail: tile NT-2 stages nothing (3 left), tile NT-1 VM(0).
// Write hazard: stage(t+2) writes buf last read at t-1; those reads are
// consumed by t-1's MFMAs before BAR(t) -> one-barrier separation holds.
// Swizzle: R9's verified map (conflicts == 0, absmax ok). 64-B rows, 4
// granules: stored slot (tid&3) at lds row tid>>2 holds global granule
// (tid&3)^((tid>>3)&3); read slot = kq ^ ((fr>>1)&3) (row-term vanishes:
// 16*mm and 64*w* are ≡ 0 mod 8 so (row>>1)&3 == (fr>>1)&3).
// 16x16x64 MFMA: 16 independent acc chains per tile (depth 1) = max ILP.

#define BAR() do { __builtin_amdgcn_sched_barrier(0); \
                   asm volatile("" ::: "memory"); \
                   __builtin_amdgcn_s_barrier(); \
                   asm volatile("" ::: "memory"); \
                   __builtin_amdgcn_sched_barrier(0); } while (0)
#define VM(n) asm volatile("s_waitcnt vmcnt(" #n ")" ::: "memory")

#define LDSBUF 24576  // A 256x64 (16384) + B 128x64 (8192)

__global__ __launch_bounds__(512, 4) void gemm_kernel(
    const signed char* __restrict__ A,   // [M][K] i8 (xq)
    const signed char* __restrict__ B,   // [N][K] i8 ternary (wq)
    const float* __restrict__ scale, const float* __restrict__ bias,
    const float* __restrict__ sx,
    float* __restrict__ C, int M, int N, int K) {
  __shared__ signed char lds[3 * LDSBUF];

  const int tid  = threadIdx.x;
  const int lane = tid & 63;
  const int wid  = tid >> 6;   // 0..7
  const int wm   = wid >> 1;   // 0..3 (64-row strip)
  const int wn   = wid & 1;    // 0..1 (64-col strip)
  const int fr   = lane & 15;
  const int kq   = lane >> 4;

  // chunked XCD swizzle (grid 1024 % 8 == 0)
  const int nwg = gridDim.x;
  const int cpx = nwg >> 3;
  const int swz = (blockIdx.x & 7) * cpx + (blockIdx.x >> 3);
  const int NBN = N >> 7;                 // 16 col tiles
  const int bn = swz % NBN;
  const int bm = swz / NBN;
  const int mBase = bm * 256, nBase = bn * 128;

  const size_t Kb = (size_t)K;

  // staging: thread t -> lds row t>>2 (A: +128*i), granule slot t&3;
  // XOR-inverse source granule; row delta 128 keeps ((row>>3... invariant.
  const int gsrc = (tid & 3) ^ ((tid >> 3) & 3);
  const char* Abyte = (const char*)A + (size_t)(mBase + (tid >> 2)) * Kb + gsrc * 16;
  const char* Bbyte = (const char*)B + (size_t)(nBase + (tid >> 2)) * Kb + gsrc * 16;

#define STAGE(off, t) do { \
    _Pragma("unroll") for (int i_ = 0; i_ < 2; ++i_) \
      __builtin_amdgcn_global_load_lds( \
        (const __attribute__((address_space(1))) void*)(Abyte + (size_t)(128 * i_) * Kb + (size_t)(t) * 64), \
        (__attribute__((address_space(3))) void*)(&lds[(off) + i_ * 8192 + tid * 16]), 16, 0, 0); \
    __builtin_amdgcn_global_load_lds( \
      (const __attribute__((address_space(1))) void*)(Bbyte + (size_t)(t) * 64), \
      (__attribute__((address_space(3))) void*)(&lds[(off) + 16384 + tid * 16]), 16, 0, 0); \
  } while (0)

  // reader constants
  const int aSlot = ((kq ^ ((fr >> 1) & 3)) << 4);
  const int aRowB = (wm * 64 + fr) * 64;            // + mm*1024
  const int bRowB = 16384 + (wn * 64 + fr) * 64;    // + nn*1024

  i32x4 aF[4], bF[4];
  i32x4 acc[4][4];
#pragma unroll
  for (int m = 0; m < 4; ++m)
#pragma unroll
    for (int n = 0; n < 4; ++n) acc[m][n] = (i32x4){0, 0, 0, 0};

#define READS(off) do { \
    _Pragma("unroll") for (int mm = 0; mm < 4; ++mm) \
      aF[mm] = *(const i32x4*)&lds[(off) + aRowB + mm * 1024 + aSlot]; \
    _Pragma("unroll") for (int nn = 0; nn < 4; ++nn) \
      bF[nn] = *(const i32x4*)&lds[(off) + bRowB + nn * 1024 + aSlot]; \
  } while (0)

#define MFMAS() do { \
    __builtin_amdgcn_s_setprio(1); \
    _Pragma("unroll") for (int mm = 0; mm < 4; ++mm) \
    _Pragma("unroll") for (int nn = 0; nn < 4; ++nn) \
      acc[mm][nn] = __builtin_amdgcn_mfma_i32_16x16x64_i8( \
          aF[mm], bF[nn], acc[mm][nn], 0, 0, 0); \
    __builtin_amdgcn_s_setprio(0); } while (0)

  // ---- prologue: tiles 0,1 staged (6 loads) ----
  STAGE(0, 0);
  STAGE(LDSBUF, 1);
  unsigned int oRd = 0, oMid = LDSBUF, oWr = 2 * LDSBUF;

  const int NT = K >> 6;  // 2048/64 = 32 K-tiles
  for (int t = 0; t < NT - 2; ++t) {
    VM(3); BAR();
    STAGE(oWr, t + 2);
    READS(oRd);
    MFMAS();
    const unsigned int tmp = oRd; oRd = oMid; oMid = oWr; oWr = tmp;
  }
  // tile NT-2: nothing left to stage
  VM(3); BAR();
  READS(oRd);
  MFMAS();
  { const unsigned int tmp = oRd; oRd = oMid; oMid = oWr; oWr = tmp; }
  // tile NT-1: drain all
  VM(0); BAR();
  READS(oRd);
  MFMAS();

  // ---- epilogue ----
  const int crowBase = mBase + wm * 64 + kq * 4;
  const int ccolBase = nBase + wn * 64 + fr;
#pragma unroll
  for (int mm = 0; mm < 4; ++mm) {
    const int r0 = crowBase + mm * 16;
    float sxv[4];
#pragma unroll
    for (int r = 0; r < 4; ++r) sxv[r] = sx[r0 + r];
#pragma unroll
    for (int nn = 0; nn < 4; ++nn) {
      const int gc = ccolBase + nn * 16;
      const float sc = scale[gc];
      const float bi = bias[gc];
#pragma unroll
      for (int r = 0; r < 4; ++r)
        C[(size_t)(r0 + r) * (size_t)N + (size_t)gc] =
            (float)acc[mm][nn][r] * (sxv[r] * sc) + bi;
    }
  }
#undef STAGE
#undef READS
#undef MFMAS
}

extern "C" void kernel_launch(void* const* d_in, const int* in_sizes, int n_in,
                              void* d_out, int out_size, void* d_ws, size_t ws_size,
                              hipStream_t stream) {
  const float* x         = (const float*)d_in[0];  // [B,S,Din]
  const float* weight    = (const float*)d_in[1];  // [Dout,Din]
  const float* row_scale = (const float*)d_in[2];  // [Dout,1]
  const float* bias      = (const float*)d_in[3];  // [Dout]
  const float* g         = (const float*)d_in[4];  // [Din]
  float* out = (float*)d_out;

  const int Din  = in_sizes[4];         // 2048
  const int Dout = in_sizes[3];         // 2048
  const int Mrows = in_sizes[0] / Din;  // 16384

  // ws: wq i8 [Dout*Din] | xq i8 [M*Din] | scale f32 [Dout] | sx f32 [M]
  char* ws = (char*)d_ws;
  signed char* wq = (signed char*)ws;
  signed char* xq = (signed char*)(ws + (size_t)Dout * Din);
  float* scale = (float*)(ws + (size_t)Dout * Din + (size_t)Mrows * Din);
  float* sx = scale + Dout;

  prep_kernel<<<Dout + Mrows, 256, 0, stream>>>(x, g, weight, row_scale,
                                                xq, sx, wq, scale, Din, Dout);
  const int grid = (Mrows / 256) * (Dout / 128);  // 64 * 16 = 1024
  gemm_kernel<<<grid, 512, 0, stream>>>(xq, wq, scale, bias, sx, out,
                                        Mrows, Dout, Din);
}